// Round 1
// baseline (553.433 us; speedup 1.0000x reference)
//
#include <hip/hip_runtime.h>

#define M_PATCH 676
#define K_DIM   384
#define N_LIB   100000
#define BM      128
#define BN      128
#define BK      32
#define LDT     40            // padded LDS row stride in shorts (80B) to spread banks
#define NCH     782           // ceil(100000/128)
#define MTILES  6
#define N_PAD   (NCH*BN)      // 100096
#define IMG     224
#define FMAP    26
#define KS      33
#define KHALF   16

typedef __attribute__((ext_vector_type(4))) float  f32x4;
typedef __attribute__((ext_vector_type(8))) short  short8;

static __device__ __forceinline__ unsigned short f2bf(float f) {
  unsigned u = __float_as_uint(f);
  u = u + 0x7FFFu + ((u >> 16) & 1u);   // RNE; inputs finite
  return (unsigned short)(u >> 16);
}

static __device__ __forceinline__ unsigned long long shfl_xor_u64(unsigned long long v, int m) {
  unsigned lo = (unsigned)v, hi = (unsigned)(v >> 32);
  lo = __shfl_xor(lo, m, 64);
  hi = __shfl_xor(hi, m, 64);
  return ((unsigned long long)hi << 32) | lo;
}

static __device__ __forceinline__ unsigned long long umin64(unsigned long long a, unsigned long long b) { return a < b ? a : b; }
static __device__ __forceinline__ unsigned long long umax64(unsigned long long a, unsigned long long b) { return a > b ? a : b; }

// ---------------- K1: row norms (fp32). y2 padded with +inf for n>=N_LIB ----------------
__global__ void pc_norms_kernel(const float* __restrict__ patch, const float* __restrict__ lib,
                                float* __restrict__ y2, float* __restrict__ x2) {
  const int w = threadIdx.x >> 6, lane = threadIdx.x & 63;
  const long r = (long)blockIdx.x * 4 + w;
  if (r < N_PAD) {
    float s;
    if (r < N_LIB) {
      const float* p = lib + r * K_DIM;
      s = 0.f;
      #pragma unroll
      for (int j = 0; j < 6; ++j) { float v = p[lane + 64 * j]; s += v * v; }
      #pragma unroll
      for (int m = 1; m < 64; m <<= 1) s += __shfl_xor(s, m, 64);
    } else {
      s = __builtin_inff();
    }
    if (lane == 0) y2[r] = s;
  } else {
    const long pr = r - N_PAD;
    if (pr < M_PATCH) {
      const float* p = patch + pr * K_DIM;
      float s = 0.f;
      #pragma unroll
      for (int j = 0; j < 6; ++j) { float v = p[lane + 64 * j]; s += v * v; }
      #pragma unroll
      for (int m = 1; m < 64; m <<= 1) s += __shfl_xor(s, m, 64);
      if (lane == 0) x2[pr] = s;
    }
  }
}

// ---------------- K2: bf16 MFMA GEMM + fused per-row min over the block's 128 cols -------
// grid = (MTILES, NCH): consecutive blocks share the B chunk -> L2 reuse.
__launch_bounds__(256, 2)
__global__ void pc_gemm_min_kernel(const float* __restrict__ A, const float* __restrict__ B,
                                   const float* __restrict__ x2g, const float* __restrict__ y2g,
                                   unsigned long long* __restrict__ partial) {
  __shared__ union SMem {
    struct { short As[BM * LDT]; short Bs[BN * LDT]; } st;
    unsigned long long red[BM * 32];
  } sm;
  __shared__ float x2s[BM];
  __shared__ float y2s[BN];

  const int t  = threadIdx.x;
  const int m0 = blockIdx.x * BM;
  const int n0 = blockIdx.y * BN;

  if (t < BM) {
    const int gm = m0 + t;
    x2s[t] = (gm < M_PATCH) ? x2g[gm] : 0.f;
    y2s[t] = y2g[n0 + t];
  }

  const int c4 = t & 7;   // float4 slot within a 32-wide k chunk
  const int br = t >> 3;  // base row 0..31

  const float* pA[4]; const float* pB[4];
  int vA[4], vB[4];
  #pragma unroll
  for (int j = 0; j < 4; ++j) {
    const int row = br + 32 * j;
    const int gm = m0 + row, gn = n0 + row;
    vA[j] = (gm < M_PATCH);
    vB[j] = (gn < N_LIB);
    pA[j] = A + (long)gm * K_DIM + c4 * 4;
    pB[j] = B + (long)gn * K_DIM + c4 * 4;
  }

  f32x4 acc[4][4];
  #pragma unroll
  for (int i = 0; i < 4; ++i) {
    #pragma unroll
    for (int j = 0; j < 4; ++j) acc[i][j] = (f32x4){0.f, 0.f, 0.f, 0.f};
  }

  const int wid  = t >> 6;
  const int lane = t & 63;
  const int wm = wid >> 1, wn = wid & 1;
  const int quad = lane >> 4;
  const int l15  = lane & 15;

  for (int ks = 0; ks < K_DIM / BK; ++ks) {
    const int koff = ks * BK;
    __syncthreads();
    #pragma unroll
    for (int j = 0; j < 4; ++j) {
      float4 v = make_float4(0.f, 0.f, 0.f, 0.f);
      if (vA[j]) v = *(const float4*)(pA[j] + koff);
      ushort4 h = make_ushort4(f2bf(v.x), f2bf(v.y), f2bf(v.z), f2bf(v.w));
      *(ushort4*)(&sm.st.As[(br + 32 * j) * LDT + c4 * 4]) = h;
    }
    #pragma unroll
    for (int j = 0; j < 4; ++j) {
      float4 v = make_float4(0.f, 0.f, 0.f, 0.f);
      if (vB[j]) v = *(const float4*)(pB[j] + koff);
      ushort4 h = make_ushort4(f2bf(v.x), f2bf(v.y), f2bf(v.z), f2bf(v.w));
      *(ushort4*)(&sm.st.Bs[(br + 32 * j) * LDT + c4 * 4]) = h;
    }
    __syncthreads();

    short8 af[4], bf[4];
    #pragma unroll
    for (int mi = 0; mi < 4; ++mi)
      af[mi] = *(const short8*)(&sm.st.As[(wm * 64 + mi * 16 + l15) * LDT + quad * 8]);
    #pragma unroll
    for (int ni = 0; ni < 4; ++ni)
      bf[ni] = *(const short8*)(&sm.st.Bs[(wn * 64 + ni * 16 + l15) * LDT + quad * 8]);

    #pragma unroll
    for (int mi = 0; mi < 4; ++mi) {
      #pragma unroll
      for (int ni = 0; ni < 4; ++ni)
        acc[mi][ni] = __builtin_amdgcn_mfma_f32_16x16x32_bf16(af[mi], bf[ni], acc[mi][ni], 0, 0, 0);
    }
  }

  __syncthreads();   // protect union: all LDS frag reads done before red[] writes

  // Per-lane: for each owned row, min over the 4 ni cols; write to red[row][colgroup].
  #pragma unroll
  for (int mi = 0; mi < 4; ++mi) {
    #pragma unroll
    for (int r = 0; r < 4; ++r) {
      const int row_l = wm * 64 + mi * 16 + quad * 4 + r;
      const float xs = x2s[row_l];
      unsigned long long kmin = ~0ull;
      #pragma unroll
      for (int ni = 0; ni < 4; ++ni) {
        const int col_l = wn * 64 + ni * 16 + l15;
        float d2 = xs + y2s[col_l] - 2.0f * acc[mi][ni][r];
        d2 = fmaxf(d2, 0.0f);
        const unsigned long long key =
            ((unsigned long long)__float_as_uint(d2) << 32) | (unsigned)(n0 + col_l);
        kmin = umin64(kmin, key);
      }
      sm.red[row_l * 32 + wn * 16 + l15] = kmin;
    }
  }
  __syncthreads();
  if (t < BM) {
    unsigned long long k = ~0ull;
    #pragma unroll 8
    for (int c = 0; c < 32; ++c) k = umin64(k, sm.red[t * 32 + c]);
    partial[(long)(m0 + t) * NCH + blockIdx.y] = k;
  }
}

// ---------------- K3: reduce partials -> min_val (sqrt) + min_idx per patch row ----------
__global__ void pc_reduce_kernel(const unsigned long long* __restrict__ partial,
                                 float* __restrict__ minval, unsigned* __restrict__ minidx) {
  const int m = blockIdx.x;
  const int t = threadIdx.x;  // 128
  unsigned long long k = ~0ull;
  for (int c = t; c < NCH; c += 128) k = umin64(k, partial[(long)m * NCH + c]);
  #pragma unroll
  for (int off = 1; off < 64; off <<= 1) k = umin64(k, shfl_xor_u64(k, off));
  __shared__ unsigned long long sh[2];
  if ((t & 63) == 0) sh[t >> 6] = k;
  __syncthreads();
  if (t == 0) {
    k = umin64(sh[0], sh[1]);
    const float d2 = __uint_as_float((unsigned)(k >> 32));
    minval[m] = sqrtf(fmaxf(d2, 0.f));
    minidx[m] = (unsigned)k;
  }
}

// ---------------- K4: argmax over min_val -> s_idx, s_star, m_star row -------------------
__global__ void pc_select_kernel(const float* __restrict__ minval, const unsigned* __restrict__ minidx,
                                 unsigned* __restrict__ scal) {
  const int t = threadIdx.x;  // 256
  unsigned long long k = 0ull;
  for (int m = t; m < M_PATCH; m += 256) {
    const unsigned long long key =
        ((unsigned long long)__float_as_uint(minval[m]) << 32) | (0xFFFFFFFFu - (unsigned)m);
    k = umax64(k, key);
  }
  #pragma unroll
  for (int off = 1; off < 64; off <<= 1) k = umax64(k, shfl_xor_u64(k, off));
  __shared__ unsigned long long sh[4];
  if ((t & 63) == 0) sh[t >> 6] = k;
  __syncthreads();
  if (t == 0) {
    #pragma unroll
    for (int w = 1; w < 4; ++w) k = umax64(k, sh[w]);
    const unsigned m = 0xFFFFFFFFu - (unsigned)k;
    scal[0] = m;                   // s_idx
    scal[1] = (unsigned)(k >> 32); // s_star bits (already sqrt'd)
    scal[2] = minidx[m];           // m_star row in lib
  }
}

// ---------------- K5: exact fp32 squared distance m_star vs lib --------------------------
__global__ void pc_wdist_kernel(const float* __restrict__ lib, const unsigned* __restrict__ scal,
                                float* __restrict__ wd) {
  const int w = threadIdx.x >> 6, lane = threadIdx.x & 63;
  const long r = (long)blockIdx.x * 4 + w;
  if (r >= N_LIB) return;
  const float* ms = lib + (long)scal[2] * K_DIM;
  const float* p  = lib + r * K_DIM;
  float s = 0.f;
  #pragma unroll
  for (int j = 0; j < 6; ++j) { float d = p[lane + 64 * j] - ms[lane + 64 * j]; s += d * d; }
  #pragma unroll
  for (int m = 1; m < 64; m <<= 1) s += __shfl_xor(s, m, 64);
  if (lane == 0) wd[r] = s;  // squared; ordering identical to norm
}

// ---------------- K6: 3-pass first-min top-3 (matches lax.top_k tie order) ---------------
__global__ void pc_top3_kernel(const float* __restrict__ wd, unsigned* __restrict__ scal) {
  __shared__ unsigned ex[3];
  __shared__ unsigned long long shm[16];
  const int t = threadIdx.x;  // 1024
  for (int p = 0; p < 3; ++p) {
    const unsigned e0 = (p > 0) ? ex[0] : 0xFFFFFFFFu;
    const unsigned e1 = (p > 1) ? ex[1] : 0xFFFFFFFFu;
    unsigned long long k = ~0ull;
    for (int n = t; n < N_LIB; n += 1024) {
      if ((unsigned)n == e0 || (unsigned)n == e1) continue;
      const unsigned long long key = ((unsigned long long)__float_as_uint(wd[n]) << 32) | (unsigned)n;
      k = umin64(k, key);
    }
    #pragma unroll
    for (int off = 1; off < 64; off <<= 1) k = umin64(k, shfl_xor_u64(k, off));
    if ((t & 63) == 0) shm[t >> 6] = k;
    __syncthreads();
    if (t == 0) {
      #pragma unroll
      for (int w = 1; w < 16; ++w) k = umin64(k, shm[w]);
      ex[p] = (unsigned)k;
    }
    __syncthreads();
  }
  if (t == 0) { scal[3] = ex[1]; scal[4] = ex[2]; }
}

// ---------------- K7: final anomaly score s ----------------------------------------------
__global__ void pc_final_kernel(const float* __restrict__ patch, const float* __restrict__ lib,
                                const unsigned* __restrict__ scal, float* __restrict__ out) {
  const int w = threadIdx.x >> 6, lane = threadIdx.x & 63;
  __shared__ float sh[2];
  const unsigned nn = scal[3 + w];
  const float* mt = patch + (long)scal[0] * K_DIM;
  const float* pv = lib + (long)nn * K_DIM;
  float s = 0.f;
  #pragma unroll
  for (int j = 0; j < 6; ++j) { float d = mt[lane + 64 * j] - pv[lane + 64 * j]; s += d * d; }
  #pragma unroll
  for (int m = 1; m < 64; m <<= 1) s += __shfl_xor(s, m, 64);
  if (lane == 0) sh[w] = s;
  __syncthreads();
  if (threadIdx.x == 0) {
    const float D = sqrtf((float)K_DIM);
    const float s_star = __uint_as_float(scal[1]);
    const float a = sqrtf(sh[0]), b = sqrtf(sh[1]);
    const float wgt = 1.f - expf(s_star / D) / (expf(a / D) + expf(b / D));
    out[0] = wgt * s_star;
  }
}

// ---------------- K8: bilinear 26x26 -> 224x224 (half-pixel, clamp) ----------------------
__global__ void pc_upsample_kernel(const float* __restrict__ mv, float* __restrict__ up) {
  const int idx = blockIdx.x * 256 + threadIdx.x;
  if (idx >= IMG * IMG) return;
  const int y = idx / IMG, x = idx - y * IMG;
  const float scale = (float)FMAP / (float)IMG;
  const float fy = ((float)y + 0.5f) * scale - 0.5f;
  const float fx = ((float)x + 0.5f) * scale - 0.5f;
  const int iy0 = (int)floorf(fy); const float ty = fy - (float)iy0;
  const int ix0 = (int)floorf(fx); const float tx = fx - (float)ix0;
  const int y0 = min(max(iy0, 0), FMAP - 1), y1 = min(max(iy0 + 1, 0), FMAP - 1);
  const int x0 = min(max(ix0, 0), FMAP - 1), x1 = min(max(ix0 + 1, 0), FMAP - 1);
  const float v00 = mv[y0 * FMAP + x0], v01 = mv[y0 * FMAP + x1];
  const float v10 = mv[y1 * FMAP + x0], v11 = mv[y1 * FMAP + x1];
  const float v0 = v00 + (v01 - v00) * tx;
  const float v1 = v10 + (v11 - v10) * tx;
  up[idx] = v0 + (v1 - v0) * ty;
}

// ---------------- K9/K10: separable 33-tap gaussian, reflect indexing --------------------
static __device__ __forceinline__ int pc_refl(int i) {
  return i < 0 ? -i : (i >= IMG ? 2 * IMG - 2 - i : i);
}

__global__ void pc_blur_kernel(const float* __restrict__ src, float* __restrict__ dst, int along_x) {
  __shared__ double kd[KS];
  __shared__ double ksum;
  __shared__ float kf[KS];
  const int t = threadIdx.x;
  if (t < KS) { const double xx = (double)(t - KHALF) / 4.0; kd[t] = exp(-0.5 * xx * xx); }
  __syncthreads();
  if (t == 0) { double s = 0.0; for (int i = 0; i < KS; ++i) s += kd[i]; ksum = s; }
  __syncthreads();
  if (t < KS) kf[t] = (float)(kd[t] / ksum);
  __syncthreads();
  const int idx = blockIdx.x * 256 + t;
  if (idx >= IMG * IMG) return;
  const int y = idx / IMG, x = idx - y * IMG;
  float s = 0.f;
  if (along_x) {
    #pragma unroll
    for (int i = 0; i < KS; ++i) s += kf[i] * src[y * IMG + pc_refl(x + i - KHALF)];
  } else {
    #pragma unroll
    for (int i = 0; i < KS; ++i) s += kf[i] * src[pc_refl(y + i - KHALF) * IMG + x];
  }
  dst[idx] = s;
}

extern "C" void kernel_launch(void* const* d_in, const int* in_sizes, int n_in,
                              void* d_out, int out_size, void* d_ws, size_t ws_size,
                              hipStream_t stream) {
  const float* patch = (const float*)d_in[0];
  const float* lib   = (const float*)d_in[1];
  float* out = (float*)d_out;

  char* p = (char*)d_ws;
  auto take = [&](size_t n) { char* q = p; p += (n + 511) & ~(size_t)511; return q; };
  float* y2        = (float*)take((size_t)N_PAD * 4);
  float* x2        = (float*)take((size_t)M_PATCH * 4);
  unsigned long long* partial = (unsigned long long*)take((size_t)MTILES * BM * NCH * 8);
  float* minval    = (float*)take((size_t)M_PATCH * 4);
  unsigned* minidx = (unsigned*)take((size_t)M_PATCH * 4);
  unsigned* scal   = (unsigned*)take(64);
  float* wd        = (float*)take((size_t)N_LIB * 4);
  float* up        = (float*)take((size_t)IMG * IMG * 4);
  float* tmpb      = (float*)take((size_t)IMG * IMG * 4);
  (void)ws_size; (void)in_sizes; (void)n_in; (void)out_size;

  const int norm_rows = N_PAD + M_PATCH;                 // 100772
  pc_norms_kernel<<<(norm_rows + 3) / 4, 256, 0, stream>>>(patch, lib, y2, x2);

  dim3 g(MTILES, NCH);
  pc_gemm_min_kernel<<<g, 256, 0, stream>>>(patch, lib, x2, y2, partial);

  pc_reduce_kernel<<<M_PATCH, 128, 0, stream>>>(partial, minval, minidx);
  pc_select_kernel<<<1, 256, 0, stream>>>(minval, minidx, scal);
  pc_wdist_kernel<<<(N_LIB + 3) / 4, 256, 0, stream>>>(lib, scal, wd);
  pc_top3_kernel<<<1, 1024, 0, stream>>>(wd, scal);
  pc_final_kernel<<<1, 128, 0, stream>>>(patch, lib, scal, out);

  pc_upsample_kernel<<<(IMG * IMG + 255) / 256, 256, 0, stream>>>(minval, up);
  pc_blur_kernel<<<(IMG * IMG + 255) / 256, 256, 0, stream>>>(up, tmpb, 0);
  pc_blur_kernel<<<(IMG * IMG + 255) / 256, 256, 0, stream>>>(tmpb, out + 1, 1);
}

// Round 2
// 390.924 us; speedup vs baseline: 1.4157x; 1.4157x over previous
//
#include <hip/hip_runtime.h>

#define M_PATCH 676
#define K_DIM   384
#define N_LIB   100000
#define BM      128
#define BN      128
#define BK      32
#define LDT     40            // padded LDS stride for the f32 fallback kernel
#define NCH     782           // ceil(100000/128)
#define MTILES  6
#define M_PAD   (MTILES*BM)   // 768
#define N_PAD   (NCH*BN)      // 100096
#define NTOPB   1563          // ceil(100000/64)
#define NCAND   (NTOPB*3)
#define IMG     224
#define FMAP    26
#define KS      33
#define KHALF   16

typedef __attribute__((ext_vector_type(4))) float  f32x4;
typedef __attribute__((ext_vector_type(8))) short  short8;
typedef unsigned long long ull;

static __device__ __forceinline__ unsigned short f2bf(float f) {
  unsigned u = __float_as_uint(f);
  u = u + 0x7FFFu + ((u >> 16) & 1u);   // RNE; inputs finite
  return (unsigned short)(u >> 16);
}

static __device__ __forceinline__ ull shfl_xor_u64(ull v, int m) {
  unsigned lo = (unsigned)v, hi = (unsigned)(v >> 32);
  lo = __shfl_xor(lo, m, 64);
  hi = __shfl_xor(hi, m, 64);
  return ((ull)hi << 32) | lo;
}

static __device__ __forceinline__ ull umin64(ull a, ull b) { return a < b ? a : b; }
static __device__ __forceinline__ ull umax64(ull a, ull b) { return a > b ? a : b; }

static __device__ __forceinline__ void gld16(const unsigned short* g, unsigned short* l) {
  __builtin_amdgcn_global_load_lds(
      (const __attribute__((address_space(1))) void*)g,
      (__attribute__((address_space(3))) void*)l, 16, 0, 0);
}

// ---------------- K1: row norms + bf16 conversion (padded banks) -------------------------
// grid: (N_PAD + M_PAD)/4 blocks x 256; one wave per row.
__global__ void pc_norms_cvt_kernel(const float* __restrict__ patch, const float* __restrict__ lib,
                                    float* __restrict__ y2, float* __restrict__ x2,
                                    unsigned short* __restrict__ Abf, unsigned short* __restrict__ Bbf,
                                    int do_cvt) {
  const int w = threadIdx.x >> 6, lane = threadIdx.x & 63;
  const long r = (long)blockIdx.x * 4 + w;
  if (r < N_PAD) {
    float s;
    if (r < N_LIB) {
      const float* p = lib + r * K_DIM;
      float v[6];
      s = 0.f;
      #pragma unroll
      for (int j = 0; j < 6; ++j) { v[j] = p[lane + 64 * j]; s += v[j] * v[j]; }
      if (do_cvt) {
        #pragma unroll
        for (int j = 0; j < 6; ++j) Bbf[r * K_DIM + lane + 64 * j] = f2bf(v[j]);
      }
      #pragma unroll
      for (int m = 1; m < 64; m <<= 1) s += __shfl_xor(s, m, 64);
    } else {
      s = __builtin_inff();
      if (do_cvt) {
        #pragma unroll
        for (int j = 0; j < 6; ++j) Bbf[r * K_DIM + lane + 64 * j] = 0;
      }
    }
    if (lane == 0) y2[r] = s;
  } else {
    const long pr = r - N_PAD;
    if (pr < M_PATCH) {
      const float* p = patch + pr * K_DIM;
      float v[6]; float s = 0.f;
      #pragma unroll
      for (int j = 0; j < 6; ++j) { v[j] = p[lane + 64 * j]; s += v[j] * v[j]; }
      if (do_cvt) {
        #pragma unroll
        for (int j = 0; j < 6; ++j) Abf[pr * K_DIM + lane + 64 * j] = f2bf(v[j]);
      }
      #pragma unroll
      for (int m = 1; m < 64; m <<= 1) s += __shfl_xor(s, m, 64);
      if (lane == 0) x2[pr] = s;
    } else if (pr < M_PAD) {
      if (do_cvt) {
        #pragma unroll
        for (int j = 0; j < 6; ++j) Abf[pr * K_DIM + lane + 64 * j] = 0;
      }
    }
  }
}

// ---------------- K2 (main): bf16 MFMA GEMM via global_load_lds + fused min --------------
// grid (MTILES, NCH). LDS: As/Bs 8KB each, unpadded, XOR-swizzled 16B pieces.
__launch_bounds__(256, 4)
__global__ void pc_gemm_min_bf16_kernel(const unsigned short* __restrict__ Abf,
                                        const unsigned short* __restrict__ Bbf,
                                        const float* __restrict__ x2g, const float* __restrict__ y2g,
                                        ull* __restrict__ partial) {
  __shared__ unsigned short As[BM * 32];   // row-major, 64B/row (BK=32 bf16)
  __shared__ unsigned short Bs[BN * 32];
  __shared__ float x2s[BM];
  __shared__ float y2s[BN];
  __shared__ ull red[BM * 2];

  const int t = threadIdx.x;
  const int m0 = blockIdx.x * BM;
  const int n0 = blockIdx.y * BN;
  const int wid = t >> 6, lane = t & 63;

  if (t < BM) {
    const int gm = m0 + t;
    x2s[t] = (gm < M_PATCH) ? x2g[gm] : 0.f;
    y2s[t] = y2g[n0 + t];
  }

  // Staging: wave `wid` fills chunks {wid, wid+4} of each tile (1KB per chunk = 16 rows).
  // Lane l covers row chunk*16 + (l>>2); physical 16B slot (l&3) holds logical piece
  // (l&3) ^ ((l>>4)&3)  — XOR swizzle so ds_read_b128 fragments are <=2-way per bank.
  const int srow   = (wid << 4) + (lane >> 2);
  const int spiece = (lane & 3) ^ ((lane >> 4) & 3);
  const unsigned short* gA0 = Abf + (size_t)(m0 + srow) * K_DIM + spiece * 8;
  const unsigned short* gA1 = gA0 + (size_t)64 * K_DIM;
  const unsigned short* gB0 = Bbf + (size_t)(n0 + srow) * K_DIM + spiece * 8;
  const unsigned short* gB1 = gB0 + (size_t)64 * K_DIM;
  unsigned short* lA0 = &As[wid * 512];
  unsigned short* lA1 = &As[(wid + 4) * 512];
  unsigned short* lB0 = &Bs[wid * 512];
  unsigned short* lB1 = &Bs[(wid + 4) * 512];

  f32x4 acc[4][4];
  #pragma unroll
  for (int i = 0; i < 4; ++i)
    #pragma unroll
    for (int j = 0; j < 4; ++j) acc[i][j] = (f32x4){0.f, 0.f, 0.f, 0.f};

  const int wm = wid >> 1, wn = wid & 1;
  const int quad = lane >> 4, l15 = lane & 15;
  const int poff = (quad ^ ((l15 >> 2) & 3)) * 8;   // swizzled piece offset (shorts)

  for (int ks = 0; ks < K_DIM / BK; ++ks) {
    __syncthreads();                       // frag reads of previous tile done
    gld16(gA0 + ks * BK, lA0);
    gld16(gA1 + ks * BK, lA1);
    gld16(gB0 + ks * BK, lB0);
    gld16(gB1 + ks * BK, lB1);
    __builtin_amdgcn_s_waitcnt(0);         // drain global_load_lds
    __syncthreads();

    short8 af[4], bf[4];
    #pragma unroll
    for (int mi = 0; mi < 4; ++mi)
      af[mi] = *(const short8*)&As[(wm * 64 + mi * 16 + l15) * 32 + poff];
    #pragma unroll
    for (int ni = 0; ni < 4; ++ni)
      bf[ni] = *(const short8*)&Bs[(wn * 64 + ni * 16 + l15) * 32 + poff];

    #pragma unroll
    for (int mi = 0; mi < 4; ++mi)
      #pragma unroll
      for (int ni = 0; ni < 4; ++ni)
        acc[mi][ni] = __builtin_amdgcn_mfma_f32_16x16x32_bf16(af[mi], bf[ni], acc[mi][ni], 0, 0, 0);
  }

  // Epilogue: per-row min over this block's 128 cols.
  #pragma unroll
  for (int mi = 0; mi < 4; ++mi) {
    #pragma unroll
    for (int r = 0; r < 4; ++r) {
      const int row_l = wm * 64 + mi * 16 + quad * 4 + r;
      const float xs = x2s[row_l];
      ull kmin = ~0ull;
      #pragma unroll
      for (int ni = 0; ni < 4; ++ni) {
        const int col_l = wn * 64 + ni * 16 + l15;
        float d2 = xs + y2s[col_l] - 2.0f * acc[mi][ni][r];
        d2 = fmaxf(d2, 0.0f);
        const ull key = ((ull)__float_as_uint(d2) << 32) | (unsigned)(n0 + col_l);
        kmin = umin64(kmin, key);
      }
      #pragma unroll
      for (int off = 1; off < 16; off <<= 1) kmin = umin64(kmin, shfl_xor_u64(kmin, off));
      if (l15 == 0) red[row_l * 2 + wn] = kmin;
    }
  }
  __syncthreads();
  if (t < BM) {
    const ull k = umin64(red[t * 2], red[t * 2 + 1]);
    partial[(size_t)(m0 + t) * NCH + blockIdx.y] = k;
  }
}

// ---------------- K2 (fallback, ws too small): fp32-staged GEMM (round-1 kernel) ---------
__launch_bounds__(256, 2)
__global__ void pc_gemm_min_f32_kernel(const float* __restrict__ A, const float* __restrict__ B,
                                       const float* __restrict__ x2g, const float* __restrict__ y2g,
                                       ull* __restrict__ partial) {
  __shared__ union SMem {
    struct { short As[BM * LDT]; short Bs[BN * LDT]; } st;
    ull red[BM * 32];
  } sm;
  __shared__ float x2s[BM];
  __shared__ float y2s[BN];

  const int t  = threadIdx.x;
  const int m0 = blockIdx.x * BM;
  const int n0 = blockIdx.y * BN;

  if (t < BM) {
    const int gm = m0 + t;
    x2s[t] = (gm < M_PATCH) ? x2g[gm] : 0.f;
    y2s[t] = y2g[n0 + t];
  }

  const int c4 = t & 7;
  const int br = t >> 3;

  const float* pA[4]; const float* pB[4];
  int vA[4], vB[4];
  #pragma unroll
  for (int j = 0; j < 4; ++j) {
    const int row = br + 32 * j;
    const int gm = m0 + row, gn = n0 + row;
    vA[j] = (gm < M_PATCH);
    vB[j] = (gn < N_LIB);
    pA[j] = A + (long)gm * K_DIM + c4 * 4;
    pB[j] = B + (long)gn * K_DIM + c4 * 4;
  }

  f32x4 acc[4][4];
  #pragma unroll
  for (int i = 0; i < 4; ++i)
    #pragma unroll
    for (int j = 0; j < 4; ++j) acc[i][j] = (f32x4){0.f, 0.f, 0.f, 0.f};

  const int wid  = t >> 6;
  const int lane = t & 63;
  const int wm = wid >> 1, wn = wid & 1;
  const int quad = lane >> 4;
  const int l15  = lane & 15;

  for (int ks = 0; ks < K_DIM / BK; ++ks) {
    const int koff = ks * BK;
    __syncthreads();
    #pragma unroll
    for (int j = 0; j < 4; ++j) {
      float4 v = make_float4(0.f, 0.f, 0.f, 0.f);
      if (vA[j]) v = *(const float4*)(pA[j] + koff);
      ushort4 h = make_ushort4(f2bf(v.x), f2bf(v.y), f2bf(v.z), f2bf(v.w));
      *(ushort4*)(&sm.st.As[(br + 32 * j) * LDT + c4 * 4]) = h;
    }
    #pragma unroll
    for (int j = 0; j < 4; ++j) {
      float4 v = make_float4(0.f, 0.f, 0.f, 0.f);
      if (vB[j]) v = *(const float4*)(pB[j] + koff);
      ushort4 h = make_ushort4(f2bf(v.x), f2bf(v.y), f2bf(v.z), f2bf(v.w));
      *(ushort4*)(&sm.st.Bs[(br + 32 * j) * LDT + c4 * 4]) = h;
    }
    __syncthreads();

    short8 af[4], bf[4];
    #pragma unroll
    for (int mi = 0; mi < 4; ++mi)
      af[mi] = *(const short8*)(&sm.st.As[(wm * 64 + mi * 16 + l15) * LDT + quad * 8]);
    #pragma unroll
    for (int ni = 0; ni < 4; ++ni)
      bf[ni] = *(const short8*)(&sm.st.Bs[(wn * 64 + ni * 16 + l15) * LDT + quad * 8]);

    #pragma unroll
    for (int mi = 0; mi < 4; ++mi)
      #pragma unroll
      for (int ni = 0; ni < 4; ++ni)
        acc[mi][ni] = __builtin_amdgcn_mfma_f32_16x16x32_bf16(af[mi], bf[ni], acc[mi][ni], 0, 0, 0);
  }

  __syncthreads();

  #pragma unroll
  for (int mi = 0; mi < 4; ++mi) {
    #pragma unroll
    for (int r = 0; r < 4; ++r) {
      const int row_l = wm * 64 + mi * 16 + quad * 4 + r;
      const float xs = x2s[row_l];
      ull kmin = ~0ull;
      #pragma unroll
      for (int ni = 0; ni < 4; ++ni) {
        const int col_l = wn * 64 + ni * 16 + l15;
        float d2 = xs + y2s[col_l] - 2.0f * acc[mi][ni][r];
        d2 = fmaxf(d2, 0.0f);
        const ull key = ((ull)__float_as_uint(d2) << 32) | (unsigned)(n0 + col_l);
        kmin = umin64(kmin, key);
      }
      sm.red[row_l * 32 + wn * 16 + l15] = kmin;
    }
  }
  __syncthreads();
  if (t < BM) {
    ull k = ~0ull;
    #pragma unroll 8
    for (int c = 0; c < 32; ++c) k = umin64(k, sm.red[t * 32 + c]);
    partial[(long)(m0 + t) * NCH + blockIdx.y] = k;
  }
}

// ---------------- K3: reduce partials -> min_val (sqrt) + min_idx per patch row ----------
__global__ void pc_reduce_kernel(const ull* __restrict__ partial,
                                 float* __restrict__ minval, unsigned* __restrict__ minidx) {
  const int m = blockIdx.x;
  const int t = threadIdx.x;  // 128
  ull k = ~0ull;
  for (int c = t; c < NCH; c += 128) k = umin64(k, partial[(long)m * NCH + c]);
  #pragma unroll
  for (int off = 1; off < 64; off <<= 1) k = umin64(k, shfl_xor_u64(k, off));
  __shared__ ull sh[2];
  if ((t & 63) == 0) sh[t >> 6] = k;
  __syncthreads();
  if (t == 0) {
    k = umin64(sh[0], sh[1]);
    const float d2 = __uint_as_float((unsigned)(k >> 32));
    minval[m] = sqrtf(fmaxf(d2, 0.f));
    minidx[m] = (unsigned)k;
  }
}

// ---------------- K4: argmax over min_val -> s_idx, s_star, m_star row -------------------
__global__ void pc_select_kernel(const float* __restrict__ minval, const unsigned* __restrict__ minidx,
                                 unsigned* __restrict__ scal) {
  const int t = threadIdx.x;  // 256
  ull k = 0ull;
  for (int m = t; m < M_PATCH; m += 256) {
    const ull key = ((ull)__float_as_uint(minval[m]) << 32) | (0xFFFFFFFFu - (unsigned)m);
    k = umax64(k, key);
  }
  #pragma unroll
  for (int off = 1; off < 64; off <<= 1) k = umax64(k, shfl_xor_u64(k, off));
  __shared__ ull sh[4];
  if ((t & 63) == 0) sh[t >> 6] = k;
  __syncthreads();
  if (t == 0) {
    #pragma unroll
    for (int w = 1; w < 4; ++w) k = umax64(k, sh[w]);
    const unsigned m = 0xFFFFFFFFu - (unsigned)k;
    scal[0] = m;                   // s_idx
    scal[1] = (unsigned)(k >> 32); // s_star bits (already sqrt'd)
    scal[2] = minidx[m];           // m_star row in lib
  }
}

// ---------------- K5: fp32 w_dist^2 + per-block first-min top-3 --------------------------
// grid NTOPB x 256; block covers 64 rows (wave w: rows base + w*16 .. +15).
__global__ void pc_wdist_top3_kernel(const float* __restrict__ lib, const unsigned* __restrict__ scal,
                                     ull* __restrict__ cand) {
  __shared__ ull keys[64];
  const int t = threadIdx.x, w = t >> 6, lane = t & 63;
  const float* ms = lib + (size_t)scal[2] * K_DIM;
  float msv[6];
  #pragma unroll
  for (int j = 0; j < 6; ++j) msv[j] = ms[lane + 64 * j];
  const long r0 = (long)blockIdx.x * 64 + w * 16;
  for (int i = 0; i < 16; ++i) {
    const long r = r0 + i;
    ull key = ~0ull;
    if (r < N_LIB) {
      const float* p = lib + r * K_DIM;
      float s = 0.f;
      #pragma unroll
      for (int j = 0; j < 6; ++j) { const float d = p[lane + 64 * j] - msv[j]; s += d * d; }
      #pragma unroll
      for (int m = 1; m < 64; m <<= 1) s += __shfl_xor(s, m, 64);
      key = ((ull)__float_as_uint(s) << 32) | (unsigned)r;   // squared dist: same order
    }
    if (lane == 0) keys[w * 16 + i] = key;
  }
  __syncthreads();
  if (t == 0) {
    ull picks[3];
    #pragma unroll
    for (int p = 0; p < 3; ++p) {
      ull best = ~0ull;
      for (int i = 0; i < 64; ++i) {
        const ull k = keys[i];
        if ((p > 0 && k == picks[0]) || (p > 1 && k == picks[1])) continue;
        best = umin64(best, k);
      }
      picks[p] = best;
      cand[(long)blockIdx.x * 3 + p] = best;
    }
  }
}

// ---------------- K6: merge candidates, first-min top-3 (matches lax.top_k ties) ---------
__global__ void pc_top3_merge_kernel(const ull* __restrict__ cand, unsigned* __restrict__ scal) {
  __shared__ ull shm[16];
  __shared__ ull picks_s[3];
  const int t = threadIdx.x;  // 1024
  for (int p = 0; p < 3; ++p) {
    const ull e0 = (p > 0) ? picks_s[0] : 0ull;
    const ull e1 = (p > 1) ? picks_s[1] : 0ull;
    ull k = ~0ull;
    for (int n = t; n < NCAND; n += 1024) {
      const ull c = cand[n];
      if ((p > 0 && c == e0) || (p > 1 && c == e1)) continue;
      k = umin64(k, c);
    }
    #pragma unroll
    for (int off = 1; off < 64; off <<= 1) k = umin64(k, shfl_xor_u64(k, off));
    if ((t & 63) == 0) shm[t >> 6] = k;
    __syncthreads();
    if (t == 0) {
      #pragma unroll
      for (int w = 1; w < 16; ++w) k = umin64(k, shm[w]);
      picks_s[p] = k;
    }
    __syncthreads();
  }
  if (t == 0) { scal[3] = (unsigned)picks_s[1]; scal[4] = (unsigned)picks_s[2]; }
}

// ---------------- K7: final anomaly score s ----------------------------------------------
__global__ void pc_final_kernel(const float* __restrict__ patch, const float* __restrict__ lib,
                                const unsigned* __restrict__ scal, float* __restrict__ out) {
  const int w = threadIdx.x >> 6, lane = threadIdx.x & 63;
  __shared__ float sh[2];
  const unsigned nn = scal[3 + w];
  const float* mt = patch + (long)scal[0] * K_DIM;
  const float* pv = lib + (long)nn * K_DIM;
  float s = 0.f;
  #pragma unroll
  for (int j = 0; j < 6; ++j) { const float d = mt[lane + 64 * j] - pv[lane + 64 * j]; s += d * d; }
  #pragma unroll
  for (int m = 1; m < 64; m <<= 1) s += __shfl_xor(s, m, 64);
  if (lane == 0) sh[w] = s;
  __syncthreads();
  if (threadIdx.x == 0) {
    const float D = sqrtf((float)K_DIM);
    const float s_star = __uint_as_float(scal[1]);
    const float a = sqrtf(sh[0]), b = sqrtf(sh[1]);
    const float wgt = 1.f - expf(s_star / D) / (expf(a / D) + expf(b / D));
    out[0] = wgt * s_star;
  }
}

// ---------------- K8: bilinear 26x26 -> 224x224 (half-pixel, clamp) ----------------------
__global__ void pc_upsample_kernel(const float* __restrict__ mv, float* __restrict__ up) {
  const int idx = blockIdx.x * 256 + threadIdx.x;
  if (idx >= IMG * IMG) return;
  const int y = idx / IMG, x = idx - y * IMG;
  const float scale = (float)FMAP / (float)IMG;
  const float fy = ((float)y + 0.5f) * scale - 0.5f;
  const float fx = ((float)x + 0.5f) * scale - 0.5f;
  const int iy0 = (int)floorf(fy); const float ty = fy - (float)iy0;
  const int ix0 = (int)floorf(fx); const float tx = fx - (float)ix0;
  const int y0 = min(max(iy0, 0), FMAP - 1), y1 = min(max(iy0 + 1, 0), FMAP - 1);
  const int x0 = min(max(ix0, 0), FMAP - 1), x1 = min(max(ix0 + 1, 0), FMAP - 1);
  const float v00 = mv[y0 * FMAP + x0], v01 = mv[y0 * FMAP + x1];
  const float v10 = mv[y1 * FMAP + x0], v11 = mv[y1 * FMAP + x1];
  const float v0 = v00 + (v01 - v00) * tx;
  const float v1 = v10 + (v11 - v10) * tx;
  up[idx] = v0 + (v1 - v0) * ty;
}

// ---------------- K9/K10: separable 33-tap gaussian, reflect indexing --------------------
static __device__ __forceinline__ int pc_refl(int i) {
  return i < 0 ? -i : (i >= IMG ? 2 * IMG - 2 - i : i);
}

__global__ void pc_blur_kernel(const float* __restrict__ src, float* __restrict__ dst, int along_x) {
  __shared__ double kd[KS];
  __shared__ double ksum;
  __shared__ float kf[KS];
  const int t = threadIdx.x;
  if (t < KS) { const double xx = (double)(t - KHALF) / 4.0; kd[t] = exp(-0.5 * xx * xx); }
  __syncthreads();
  if (t == 0) { double s = 0.0; for (int i = 0; i < KS; ++i) s += kd[i]; ksum = s; }
  __syncthreads();
  if (t < KS) kf[t] = (float)(kd[t] / ksum);
  __syncthreads();
  const int idx = blockIdx.x * 256 + t;
  if (idx >= IMG * IMG) return;
  const int y = idx / IMG, x = idx - y * IMG;
  float s = 0.f;
  if (along_x) {
    #pragma unroll
    for (int i = 0; i < KS; ++i) s += kf[i] * src[y * IMG + pc_refl(x + i - KHALF)];
  } else {
    #pragma unroll
    for (int i = 0; i < KS; ++i) s += kf[i] * src[pc_refl(y + i - KHALF) * IMG + x];
  }
  dst[idx] = s;
}

extern "C" void kernel_launch(void* const* d_in, const int* in_sizes, int n_in,
                              void* d_out, int out_size, void* d_ws, size_t ws_size,
                              hipStream_t stream) {
  const float* patch = (const float*)d_in[0];
  const float* lib   = (const float*)d_in[1];
  float* out = (float*)d_out;

  char* p = (char*)d_ws;
  auto take = [&](size_t n) { char* q = p; p += (n + 511) & ~(size_t)511; return q; };
  float* y2        = (float*)take((size_t)N_PAD * 4);
  float* x2        = (float*)take((size_t)M_PAD * 4);
  ull* partial     = (ull*)take((size_t)M_PAD * NCH * 8);
  float* minval    = (float*)take((size_t)M_PATCH * 4);
  unsigned* minidx = (unsigned*)take((size_t)M_PATCH * 4);
  unsigned* scal   = (unsigned*)take(64);
  ull* cand        = (ull*)take((size_t)NCAND * 8);
  float* up        = (float*)take((size_t)IMG * IMG * 4);
  float* tmpb      = (float*)take((size_t)IMG * IMG * 4);
  unsigned short* Abf = (unsigned short*)take((size_t)M_PAD * K_DIM * 2);
  unsigned short* Bbf = (unsigned short*)take((size_t)N_PAD * K_DIM * 2);
  const int use_bf16 = ((size_t)(p - (char*)d_ws) <= ws_size);
  (void)in_sizes; (void)n_in; (void)out_size;

  const int norm_rows = N_PAD + M_PAD;  // 100864
  pc_norms_cvt_kernel<<<(norm_rows + 3) / 4, 256, 0, stream>>>(patch, lib, y2, x2, Abf, Bbf, use_bf16);

  dim3 g(MTILES, NCH);
  if (use_bf16)
    pc_gemm_min_bf16_kernel<<<g, 256, 0, stream>>>(Abf, Bbf, x2, y2, partial);
  else
    pc_gemm_min_f32_kernel<<<g, 256, 0, stream>>>(patch, lib, x2, y2, partial);

  pc_reduce_kernel<<<M_PATCH, 128, 0, stream>>>(partial, minval, minidx);
  pc_select_kernel<<<1, 256, 0, stream>>>(minval, minidx, scal);
  pc_wdist_top3_kernel<<<NTOPB, 256, 0, stream>>>(lib, scal, cand);
  pc_top3_merge_kernel<<<1, 1024, 0, stream>>>(cand, scal);
  pc_final_kernel<<<1, 128, 0, stream>>>(patch, lib, scal, out);

  pc_upsample_kernel<<<(IMG * IMG + 255) / 256, 256, 0, stream>>>(minval, up);
  pc_blur_kernel<<<(IMG * IMG + 255) / 256, 256, 0, stream>>>(up, tmpb, 0);
  pc_blur_kernel<<<(IMG * IMG + 255) / 256, 256, 0, stream>>>(tmpb, out + 1, 1);
}

// Round 3
// 386.796 us; speedup vs baseline: 1.4308x; 1.0107x over previous
//
#include <hip/hip_runtime.h>

#define M_PATCH 676
#define K_DIM   384
#define N_LIB   100000
#define BM      128
#define BN      128
#define NCH     782           // ceil(100000/128)
#define MTILES  6
#define M_PAD   (MTILES*BM)   // 768
#define N_PAD   (NCH*BN)      // 100096
#define XCHUNK  98            // chunks per XCD (8*98 >= 782)
#define GRID_GEMM (8*XCHUNK*MTILES)   // 4704
#define NTOPB   1563          // ceil(100000/64)
#define NCAND   (NTOPB*3)
#define IMG     224
#define FMAP    26
#define KS      33
#define KHALF   16

typedef __attribute__((ext_vector_type(4))) float  f32x4;
typedef __attribute__((ext_vector_type(8))) short  short8;
typedef unsigned long long ull;

static __device__ __forceinline__ unsigned short f2bf(float f) {
  unsigned u = __float_as_uint(f);
  u = u + 0x7FFFu + ((u >> 16) & 1u);   // RNE; inputs finite
  return (unsigned short)(u >> 16);
}

static __device__ __forceinline__ ull shfl_xor_u64(ull v, int m) {
  unsigned lo = (unsigned)v, hi = (unsigned)(v >> 32);
  lo = __shfl_xor(lo, m, 64);
  hi = __shfl_xor(hi, m, 64);
  return ((ull)hi << 32) | lo;
}

static __device__ __forceinline__ ull umin64(ull a, ull b) { return a < b ? a : b; }
static __device__ __forceinline__ ull umax64(ull a, ull b) { return a > b ? a : b; }

static __device__ __forceinline__ void gld16(const unsigned short* g, unsigned short* l) {
  __builtin_amdgcn_global_load_lds(
      (const __attribute__((address_space(1))) void*)g,
      (__attribute__((address_space(3))) void*)l, 16, 0, 0);
}

// ---------------- K1: row norms + bf16 conversion (float2/ushort2 vectorized) ------------
// grid: (N_PAD + M_PAD)/4 blocks x 256; one wave per row.
__global__ void pc_norms_cvt_kernel(const float* __restrict__ patch, const float* __restrict__ lib,
                                    float* __restrict__ y2, float* __restrict__ x2,
                                    unsigned short* __restrict__ Abf, unsigned short* __restrict__ Bbf) {
  const int w = threadIdx.x >> 6, lane = threadIdx.x & 63;
  const long r = (long)blockIdx.x * 4 + w;
  if (r < N_PAD) {
    float s;
    if (r < N_LIB) {
      const float2* p = (const float2*)(lib + r * K_DIM);
      ushort2* q = (ushort2*)(Bbf + r * K_DIM);
      float2 v[3];
      s = 0.f;
      #pragma unroll
      for (int j = 0; j < 3; ++j) { v[j] = p[lane + 64 * j]; s += v[j].x * v[j].x + v[j].y * v[j].y; }
      #pragma unroll
      for (int j = 0; j < 3; ++j) q[lane + 64 * j] = make_ushort2(f2bf(v[j].x), f2bf(v[j].y));
      #pragma unroll
      for (int m = 1; m < 64; m <<= 1) s += __shfl_xor(s, m, 64);
    } else {
      s = __builtin_inff();
      ushort2* q = (ushort2*)(Bbf + r * K_DIM);
      #pragma unroll
      for (int j = 0; j < 3; ++j) q[lane + 64 * j] = make_ushort2(0, 0);
    }
    if (lane == 0) y2[r] = s;
  } else {
    const long pr = r - N_PAD;
    if (pr < M_PATCH) {
      const float2* p = (const float2*)(patch + pr * K_DIM);
      ushort2* q = (ushort2*)(Abf + pr * K_DIM);
      float2 v[3]; float s = 0.f;
      #pragma unroll
      for (int j = 0; j < 3; ++j) { v[j] = p[lane + 64 * j]; s += v[j].x * v[j].x + v[j].y * v[j].y; }
      #pragma unroll
      for (int j = 0; j < 3; ++j) q[lane + 64 * j] = make_ushort2(f2bf(v[j].x), f2bf(v[j].y));
      #pragma unroll
      for (int m = 1; m < 64; m <<= 1) s += __shfl_xor(s, m, 64);
      if (lane == 0) x2[pr] = s;
    } else if (pr < M_PAD) {
      ushort2* q = (ushort2*)(Abf + pr * K_DIM);
      #pragma unroll
      for (int j = 0; j < 3; ++j) q[lane + 64 * j] = make_ushort2(0, 0);
    }
  }
}

// ---------------- K2: bf16 MFMA GEMM, XCD-partitioned grid, BK=64, fused min -------------
// 1D grid GRID_GEMM. xcd = blockIdx&7 owns chunks [xcd*98, ...): its 6 m-tiles for one
// chunk are consecutive slots on the SAME XCD -> B chunk served from that XCD's L2.
__launch_bounds__(256, 4)
__global__ void pc_gemm_min_bf16_kernel(const unsigned short* __restrict__ Abf,
                                        const unsigned short* __restrict__ Bbf,
                                        const float* __restrict__ x2g, const float* __restrict__ y2g,
                                        ull* __restrict__ partial) {
  __shared__ unsigned short As[2][BM * 32];   // two 32-k sub-tiles per barrier (BK=64)
  __shared__ unsigned short Bs[2][BN * 32];
  __shared__ float x2s[BM];
  __shared__ float y2s[BN];
  __shared__ ull red[BM * 2];

  const int l = blockIdx.x;
  const int xcd = l & 7, slot = l >> 3;       // slot in [0, 588)
  const int chunk = xcd * XCHUNK + slot / MTILES;
  const int mtile = slot % MTILES;
  if (chunk >= NCH) return;

  const int t = threadIdx.x;
  const int m0 = mtile * BM;
  const int n0 = chunk * BN;
  const int wid = t >> 6, lane = t & 63;

  if (t < BM) {
    const int gm = m0 + t;
    x2s[t] = (gm < M_PATCH) ? x2g[gm] : 0.f;
    y2s[t] = y2g[n0 + t];
  }

  // Staging (per 32-k sub-tile): wave wid fills 16-row groups {wid, wid+4}.
  // Lane l covers row group*16 + (l>>2); physical 16B slot (l&3) holds logical piece
  // (l&3) ^ ((l>>4)&3) — XOR swizzle for the b128 frag reads.
  const int srow   = (wid << 4) + (lane >> 2);
  const int spiece = (lane & 3) ^ ((lane >> 4) & 3);
  const unsigned short* gA0 = Abf + (size_t)(m0 + srow) * K_DIM + spiece * 8;
  const unsigned short* gA1 = gA0 + (size_t)64 * K_DIM;
  const unsigned short* gB0 = Bbf + (size_t)(n0 + srow) * K_DIM + spiece * 8;
  const unsigned short* gB1 = gB0 + (size_t)64 * K_DIM;

  f32x4 acc[4][4];
  #pragma unroll
  for (int i = 0; i < 4; ++i)
    #pragma unroll
    for (int j = 0; j < 4; ++j) acc[i][j] = (f32x4){0.f, 0.f, 0.f, 0.f};

  const int wm = wid >> 1, wn = wid & 1;
  const int quad = lane >> 4, l15 = lane & 15;
  const int poff = (quad ^ ((l15 >> 2) & 3)) * 8;   // swizzled physical piece (shorts)

  for (int ks = 0; ks < K_DIM / 64; ++ks) {         // 6 barrier rounds
    __syncthreads();                                 // previous frag reads done
    #pragma unroll
    for (int h = 0; h < 2; ++h) {
      const int ko = ks * 64 + h * 32;
      gld16(gA0 + ko, &As[h][wid * 512]);
      gld16(gA1 + ko, &As[h][(wid + 4) * 512]);
      gld16(gB0 + ko, &Bs[h][wid * 512]);
      gld16(gB1 + ko, &Bs[h][(wid + 4) * 512]);
    }
    __builtin_amdgcn_s_waitcnt(0);                   // drain global_load_lds queue
    __syncthreads();

    #pragma unroll
    for (int h = 0; h < 2; ++h) {
      short8 af[4], bf[4];
      #pragma unroll
      for (int mi = 0; mi < 4; ++mi)
        af[mi] = *(const short8*)&As[h][(wm * 64 + mi * 16 + l15) * 32 + poff];
      #pragma unroll
      for (int ni = 0; ni < 4; ++ni)
        bf[ni] = *(const short8*)&Bs[h][(wn * 64 + ni * 16 + l15) * 32 + poff];
      #pragma unroll
      for (int mi = 0; mi < 4; ++mi)
        #pragma unroll
        for (int ni = 0; ni < 4; ++ni)
          acc[mi][ni] = __builtin_amdgcn_mfma_f32_16x16x32_bf16(af[mi], bf[ni], acc[mi][ni], 0, 0, 0);
    }
  }

  // Epilogue: per-row min over this block's 128 cols.
  #pragma unroll
  for (int mi = 0; mi < 4; ++mi) {
    #pragma unroll
    for (int r = 0; r < 4; ++r) {
      const int row_l = wm * 64 + mi * 16 + quad * 4 + r;
      const float xs = x2s[row_l];
      ull kmin = ~0ull;
      #pragma unroll
      for (int ni = 0; ni < 4; ++ni) {
        const int col_l = wn * 64 + ni * 16 + l15;
        float d2 = xs + y2s[col_l] - 2.0f * acc[mi][ni][r];
        d2 = fmaxf(d2, 0.0f);
        const ull key = ((ull)__float_as_uint(d2) << 32) | (unsigned)(n0 + col_l);
        kmin = umin64(kmin, key);
      }
      #pragma unroll
      for (int off = 1; off < 16; off <<= 1) kmin = umin64(kmin, shfl_xor_u64(kmin, off));
      if (l15 == 0) red[row_l * 2 + wn] = kmin;
    }
  }
  __syncthreads();
  if (t < BM) {
    const ull k = umin64(red[t * 2], red[t * 2 + 1]);
    partial[(size_t)chunk * M_PAD + m0 + t] = k;   // transposed: block write is contiguous 1KB
  }
}

// ---------------- K3: reduce partials -> min_val (sqrt) + min_idx per patch row ----------
__global__ void pc_reduce_kernel(const ull* __restrict__ partial,
                                 float* __restrict__ minval, unsigned* __restrict__ minidx) {
  const int m = blockIdx.x;
  const int t = threadIdx.x;  // 128
  ull k = ~0ull;
  for (int c = t; c < NCH; c += 128) k = umin64(k, partial[(size_t)c * M_PAD + m]);
  #pragma unroll
  for (int off = 1; off < 64; off <<= 1) k = umin64(k, shfl_xor_u64(k, off));
  __shared__ ull sh[2];
  if ((t & 63) == 0) sh[t >> 6] = k;
  __syncthreads();
  if (t == 0) {
    k = umin64(sh[0], sh[1]);
    const float d2 = __uint_as_float((unsigned)(k >> 32));
    minval[m] = sqrtf(fmaxf(d2, 0.f));
    minidx[m] = (unsigned)k;
  }
}

// ---------------- K4: argmax over min_val -> s_idx, s_star, m_star row -------------------
__global__ void pc_select_kernel(const float* __restrict__ minval, const unsigned* __restrict__ minidx,
                                 unsigned* __restrict__ scal) {
  const int t = threadIdx.x;  // 256
  ull k = 0ull;
  for (int m = t; m < M_PATCH; m += 256) {
    const ull key = ((ull)__float_as_uint(minval[m]) << 32) | (0xFFFFFFFFu - (unsigned)m);
    k = umax64(k, key);
  }
  #pragma unroll
  for (int off = 1; off < 64; off <<= 1) k = umax64(k, shfl_xor_u64(k, off));
  __shared__ ull sh[4];
  if ((t & 63) == 0) sh[t >> 6] = k;
  __syncthreads();
  if (t == 0) {
    #pragma unroll
    for (int w = 1; w < 4; ++w) k = umax64(k, sh[w]);
    const unsigned m = 0xFFFFFFFFu - (unsigned)k;
    scal[0] = m;                   // s_idx
    scal[1] = (unsigned)(k >> 32); // s_star bits (already sqrt'd)
    scal[2] = minidx[m];           // m_star row in lib
  }
}

// ---------------- K5: fp32 w_dist^2 + per-block first-min top-3 --------------------------
// grid NTOPB x 256; block covers 64 rows (wave w: rows base + w*16 .. +15).
__global__ void pc_wdist_top3_kernel(const float* __restrict__ lib, const unsigned* __restrict__ scal,
                                     ull* __restrict__ cand) {
  __shared__ ull keys[64];
  const int t = threadIdx.x, w = t >> 6, lane = t & 63;
  const float2* ms = (const float2*)(lib + (size_t)scal[2] * K_DIM);
  float2 msv[3];
  #pragma unroll
  for (int j = 0; j < 3; ++j) msv[j] = ms[lane + 64 * j];
  const long r0 = (long)blockIdx.x * 64 + w * 16;
  for (int i = 0; i < 16; ++i) {
    const long r = r0 + i;
    ull key = ~0ull;
    if (r < N_LIB) {
      const float2* p = (const float2*)(lib + r * K_DIM);
      float s = 0.f;
      #pragma unroll
      for (int j = 0; j < 3; ++j) {
        const float2 v = p[lane + 64 * j];
        const float dx = v.x - msv[j].x, dy = v.y - msv[j].y;
        s += dx * dx + dy * dy;
      }
      #pragma unroll
      for (int m = 1; m < 64; m <<= 1) s += __shfl_xor(s, m, 64);
      key = ((ull)__float_as_uint(s) << 32) | (unsigned)r;   // squared dist: same order
    }
    if (lane == 0) keys[w * 16 + i] = key;
  }
  __syncthreads();
  if (t == 0) {
    ull picks[3];
    #pragma unroll
    for (int p = 0; p < 3; ++p) {
      ull best = ~0ull;
      for (int i = 0; i < 64; ++i) {
        const ull k = keys[i];
        if ((p > 0 && k == picks[0]) || (p > 1 && k == picks[1])) continue;
        best = umin64(best, k);
      }
      picks[p] = best;
      cand[(long)blockIdx.x * 3 + p] = best;
    }
  }
}

// ---------------- K6: merge candidates, first-min top-3 (matches lax.top_k ties) ---------
__global__ void pc_top3_merge_kernel(const ull* __restrict__ cand, unsigned* __restrict__ scal) {
  __shared__ ull shm[16];
  __shared__ ull picks_s[3];
  const int t = threadIdx.x;  // 1024
  for (int p = 0; p < 3; ++p) {
    const ull e0 = (p > 0) ? picks_s[0] : 0ull;
    const ull e1 = (p > 1) ? picks_s[1] : 0ull;
    ull k = ~0ull;
    for (int n = t; n < NCAND; n += 1024) {
      const ull c = cand[n];
      if ((p > 0 && c == e0) || (p > 1 && c == e1)) continue;
      k = umin64(k, c);
    }
    #pragma unroll
    for (int off = 1; off < 64; off <<= 1) k = umin64(k, shfl_xor_u64(k, off));
    if ((t & 63) == 0) shm[t >> 6] = k;
    __syncthreads();
    if (t == 0) {
      #pragma unroll
      for (int w = 1; w < 16; ++w) k = umin64(k, shm[w]);
      picks_s[p] = k;
    }
    __syncthreads();
  }
  if (t == 0) { scal[3] = (unsigned)picks_s[1]; scal[4] = (unsigned)picks_s[2]; }
}

// ---------------- K7: final anomaly score s ----------------------------------------------
__global__ void pc_final_kernel(const float* __restrict__ patch, const float* __restrict__ lib,
                                const unsigned* __restrict__ scal, float* __restrict__ out) {
  const int w = threadIdx.x >> 6, lane = threadIdx.x & 63;
  __shared__ float sh[2];
  const unsigned nn = scal[3 + w];
  const float* mt = patch + (long)scal[0] * K_DIM;
  const float* pv = lib + (long)nn * K_DIM;
  float s = 0.f;
  #pragma unroll
  for (int j = 0; j < 6; ++j) { const float d = mt[lane + 64 * j] - pv[lane + 64 * j]; s += d * d; }
  #pragma unroll
  for (int m = 1; m < 64; m <<= 1) s += __shfl_xor(s, m, 64);
  if (lane == 0) sh[w] = s;
  __syncthreads();
  if (threadIdx.x == 0) {
    const float D = sqrtf((float)K_DIM);
    const float s_star = __uint_as_float(scal[1]);
    const float a = sqrtf(sh[0]), b = sqrtf(sh[1]);
    const float wgt = 1.f - expf(s_star / D) / (expf(a / D) + expf(b / D));
    out[0] = wgt * s_star;
  }
}

// ---------------- K8: bilinear 26x26 -> 224x224 (half-pixel, clamp) ----------------------
__global__ void pc_upsample_kernel(const float* __restrict__ mv, float* __restrict__ up) {
  const int idx = blockIdx.x * 256 + threadIdx.x;
  if (idx >= IMG * IMG) return;
  const int y = idx / IMG, x = idx - y * IMG;
  const float scale = (float)FMAP / (float)IMG;
  const float fy = ((float)y + 0.5f) * scale - 0.5f;
  const float fx = ((float)x + 0.5f) * scale - 0.5f;
  const int iy0 = (int)floorf(fy); const float ty = fy - (float)iy0;
  const int ix0 = (int)floorf(fx); const float tx = fx - (float)ix0;
  const int y0 = min(max(iy0, 0), FMAP - 1), y1 = min(max(iy0 + 1, 0), FMAP - 1);
  const int x0 = min(max(ix0, 0), FMAP - 1), x1 = min(max(ix0 + 1, 0), FMAP - 1);
  const float v00 = mv[y0 * FMAP + x0], v01 = mv[y0 * FMAP + x1];
  const float v10 = mv[y1 * FMAP + x0], v11 = mv[y1 * FMAP + x1];
  const float v0 = v00 + (v01 - v00) * tx;
  const float v1 = v10 + (v11 - v10) * tx;
  up[idx] = v0 + (v1 - v0) * ty;
}

// ---------------- K9/K10: separable 33-tap gaussian, reflect indexing --------------------
static __device__ __forceinline__ int pc_refl(int i) {
  return i < 0 ? -i : (i >= IMG ? 2 * IMG - 2 - i : i);
}

__global__ void pc_blur_kernel(const float* __restrict__ src, float* __restrict__ dst, int along_x) {
  __shared__ double kd[KS];
  __shared__ double ksum;
  __shared__ float kf[KS];
  const int t = threadIdx.x;
  if (t < KS) { const double xx = (double)(t - KHALF) / 4.0; kd[t] = exp(-0.5 * xx * xx); }
  __syncthreads();
  if (t == 0) { double s = 0.0; for (int i = 0; i < KS; ++i) s += kd[i]; ksum = s; }
  __syncthreads();
  if (t < KS) kf[t] = (float)(kd[t] / ksum);
  __syncthreads();
  const int idx = blockIdx.x * 256 + t;
  if (idx >= IMG * IMG) return;
  const int y = idx / IMG, x = idx - y * IMG;
  float s = 0.f;
  if (along_x) {
    #pragma unroll
    for (int i = 0; i < KS; ++i) s += kf[i] * src[y * IMG + pc_refl(x + i - KHALF)];
  } else {
    #pragma unroll
    for (int i = 0; i < KS; ++i) s += kf[i] * src[pc_refl(y + i - KHALF) * IMG + x];
  }
  dst[idx] = s;
}

extern "C" void kernel_launch(void* const* d_in, const int* in_sizes, int n_in,
                              void* d_out, int out_size, void* d_ws, size_t ws_size,
                              hipStream_t stream) {
  const float* patch = (const float*)d_in[0];
  const float* lib   = (const float*)d_in[1];
  float* out = (float*)d_out;

  char* p = (char*)d_ws;
  auto take = [&](size_t n) { char* q = p; p += (n + 511) & ~(size_t)511; return q; };
  float* y2        = (float*)take((size_t)N_PAD * 4);
  float* x2        = (float*)take((size_t)M_PAD * 4);
  ull* partial     = (ull*)take((size_t)NCH * M_PAD * 8);
  float* minval    = (float*)take((size_t)M_PATCH * 4);
  unsigned* minidx = (unsigned*)take((size_t)M_PATCH * 4);
  unsigned* scal   = (unsigned*)take(64);
  ull* cand        = (ull*)take((size_t)NCAND * 8);
  float* up        = (float*)take((size_t)IMG * IMG * 4);
  float* tmpb      = (float*)take((size_t)IMG * IMG * 4);
  unsigned short* Abf = (unsigned short*)take((size_t)M_PAD * K_DIM * 2);
  unsigned short* Bbf = (unsigned short*)take((size_t)N_PAD * K_DIM * 2);
  (void)in_sizes; (void)n_in; (void)out_size; (void)ws_size;

  const int norm_rows = N_PAD + M_PAD;  // 100864
  pc_norms_cvt_kernel<<<(norm_rows + 3) / 4, 256, 0, stream>>>(patch, lib, y2, x2, Abf, Bbf);

  pc_gemm_min_bf16_kernel<<<GRID_GEMM, 256, 0, stream>>>(Abf, Bbf, x2, y2, partial);

  pc_reduce_kernel<<<M_PATCH, 128, 0, stream>>>(partial, minval, minidx);
  pc_select_kernel<<<1, 256, 0, stream>>>(minval, minidx, scal);
  pc_wdist_top3_kernel<<<NTOPB, 256, 0, stream>>>(lib, scal, cand);
  pc_top3_merge_kernel<<<1, 1024, 0, stream>>>(cand, scal);
  pc_final_kernel<<<1, 128, 0, stream>>>(patch, lib, scal, out);

  pc_upsample_kernel<<<(IMG * IMG + 255) / 256, 256, 0, stream>>>(minval, up);
  pc_blur_kernel<<<(IMG * IMG + 255) / 256, 256, 0, stream>>>(up, tmpb, 0);
  pc_blur_kernel<<<(IMG * IMG + 255) / 256, 256, 0, stream>>>(tmpb, out + 1, 1);
}